// Round 13
// baseline (1224.241 us; speedup 1.0000x reference)
//
#include <hip/hip_runtime.h>
#include <hip/hip_bf16.h>

typedef _Float16 f16;
typedef _Float16 f16x8 __attribute__((ext_vector_type(8)));
typedef _Float16 f16x4v __attribute__((ext_vector_type(4)));
typedef _Float16 h2 __attribute__((ext_vector_type(2)));
typedef float f32x4 __attribute__((ext_vector_type(4)));
typedef unsigned ui4v __attribute__((ext_vector_type(4)));
typedef unsigned long long ull;

#define B_ 8
#define S_ 512
#define H_ 768
#define V_ 35004
#define J_ 30
#define K_ 9
#define R_ 2160          // out rows, r = b*270 + j*9 + t
#define H3 2304
#define VMT 17           // vocab M tiles
#define VNT 274          // vocab N tiles
#define NTILE (VMT * VNT)

// ctl layout (ints): [0]=queue idx, [32]=prepdone, [64]=grudone, [256..447]=prog[chain*24+blk]
#define CTL_INTS 512

// ---------------------------------------------------------------- prep kernels

__global__ void k_zero(int* p, int n) {
    int i = blockIdx.x * 256 + threadIdx.x;
    if (i < n) p[i] = 0;
}

__global__ void k_cast(const float* __restrict__ s, f16* __restrict__ d, long n) {
    for (long i = (long)blockIdx.x * 256 + threadIdx.x; i < n; i += (long)gridDim.x * 256)
        d[i] = (f16)s[i];
}

// W_all[r] = (t==0) ? decoder_input[b,j,:] : embed[teacher[b,j,t-1],:]
__global__ void k_build_wall(const float* __restrict__ emb, const float* __restrict__ dec,
                             const int* __restrict__ teacher, f16* __restrict__ Wall) {
    int r = blockIdx.x;
    int b = r / 270, s = r % 270, j = s / 9, t = s % 9;
    const float* src = (t == 0) ? dec + ((long)b * J_ + j) * H_
                                : emb + (long)teacher[((long)b * J_ + j) * K_ + (t - 1)] * H_;
    f16* dst = Wall + (long)r * H_;
    for (int c = threadIdx.x; c < H_; c += 256) dst[c] = (f16)src[c];
}

// h exchange word: {seq:32 | f32 bits:32}; chain-major [chain][parity][768]
__global__ void k_init_h(const float* __restrict__ hidden, ull* __restrict__ hbuf) {
    int i = blockIdx.x * 256 + threadIdx.x;
    if (i < B_ * H_) {
        int b = i / H_, u = i % H_;
        hbuf[(long)b * 1536 + u] = (ull)__float_as_uint(hidden[i]);  // seq 0, parity 0
    }
}

// ---------------------------------------------------------------- shared GEMM helpers
typedef const __attribute__((address_space(1))) unsigned GASU;
typedef __attribute__((address_space(3))) unsigned LASU;
__device__ __forceinline__ void gld16(const f16* g, f16* l) {
    __builtin_amdgcn_global_load_lds((GASU*)g, (LASU*)l, 16, 0, 0);
}

// ---------------------------------------------------------------- f16 MFMA GEMM (m97 structure)
// C[M,N] = A[M,K] @ B[N,K]^T ; MODE 0: store, 1: store + bias[col]
template <int MODE>
__global__ __launch_bounds__(256) void k_gemm(const f16* __restrict__ A, const f16* __restrict__ Bm,
                                              float* __restrict__ C, const float* __restrict__ bias,
                                              int M, int N, int K, long sA, long sB, long sC) {
    A += (long)blockIdx.z * sA;
    Bm += (long)blockIdx.z * sB;
    C += (long)blockIdx.z * sC;
    const int m0 = blockIdx.y * 128, n0 = blockIdx.x * 128;
    __shared__ f16 As[128 * 32];
    __shared__ f16 Bs[128 * 32];
    const int tid = threadIdx.x, lane = tid & 63, wave = tid >> 6;
    const int wm = wave >> 1, wn = wave & 1;
    const int fr = lane & 15, kg = lane >> 4;
    f32x4 acc[4][4] = {};
    const int idxu = wave * 128;
    const int i0 = idxu + lane, i1 = idxu + 64 + lane;
    const int r0 = i0 >> 2, k80 = i0 & 3;
    const int r1 = i1 >> 2, k81 = i1 & 3;
    int ga0 = m0 + r0; if (ga0 >= M) ga0 = M - 1;
    int ga1 = m0 + r1; if (ga1 >= M) ga1 = M - 1;
    int gb0 = n0 + r0; if (gb0 >= N) gb0 = N - 1;
    int gb1 = n0 + r1; if (gb1 >= N) gb1 = N - 1;
    const f16* pa0 = A + (long)ga0 * K + k80 * 8;
    const f16* pa1 = A + (long)ga1 * K + k81 * 8;
    const f16* pb0 = Bm + (long)gb0 * K + k80 * 8;
    const f16* pb1 = Bm + (long)gb1 * K + k81 * 8;
    for (int kt = 0; kt < K; kt += 32) {
        gld16(pa0 + kt, As + idxu * 8);
        gld16(pa1 + kt, As + idxu * 8 + 512);
        gld16(pb0 + kt, Bs + idxu * 8);
        gld16(pb1 + kt, Bs + idxu * 8 + 512);
        __syncthreads();
        f16x8 af[4], bf[4];
#pragma unroll
        for (int m = 0; m < 4; ++m) af[m] = *(const f16x8*)(As + (wm * 64 + m * 16 + fr) * 32 + kg * 8);
#pragma unroll
        for (int n = 0; n < 4; ++n) bf[n] = *(const f16x8*)(Bs + (wn * 64 + n * 16 + fr) * 32 + kg * 8);
#pragma unroll
        for (int m = 0; m < 4; ++m)
#pragma unroll
            for (int n = 0; n < 4; ++n)
                acc[m][n] = __builtin_amdgcn_mfma_f32_16x16x32_f16(af[m], bf[n], acc[m][n], 0, 0, 0);
        __syncthreads();
    }
    const int crow = m0 + wm * 64 + (lane >> 4) * 4;
    const int ccol = n0 + wn * 64 + fr;
#pragma unroll
    for (int n = 0; n < 4; ++n) {
        int col = ccol + n * 16;
        if (col >= N) continue;
        float bv = (MODE == 1) ? bias[col] : 0.f;
#pragma unroll
        for (int m = 0; m < 4; ++m) {
#pragma unroll
            for (int q = 0; q < 4; ++q) {
                int row = crow + m * 16 + q;
                if (row < M) C[(long)row * N + col] = acc[m][n][q] + bv;
            }
        }
    }
}

// ---------------------------------------------------------------- merged hi/lo attention logits
__global__ __launch_bounds__(256) void k_attn3(const f16* __restrict__ Ahi, const f16* __restrict__ Alo,
                                               const f16* __restrict__ Bhi, const f16* __restrict__ Blo,
                                               float* __restrict__ C, int M, int N, int K,
                                               long sA, long sB, long sC) {
    const long za = (long)blockIdx.z * sA, zb = (long)blockIdx.z * sB;
    C += (long)blockIdx.z * sC;
    const int m0 = blockIdx.y * 128, n0 = blockIdx.x * 128;
    __shared__ f16 As[128 * 32];
    __shared__ f16 Bs[128 * 32];
    const int tid = threadIdx.x, lane = tid & 63, wave = tid >> 6;
    const int wm = wave >> 1, wn = wave & 1;
    const int fr = lane & 15, kg = lane >> 4;
    f32x4 acc[4][4] = {};
    const int idxu = wave * 128;
    const int i0 = idxu + lane, i1 = idxu + 64 + lane;
    const int r0 = i0 >> 2, k80 = i0 & 3;
    const int r1 = i1 >> 2, k81 = i1 & 3;
    int ga0 = m0 + r0; if (ga0 >= M) ga0 = M - 1;
    int ga1 = m0 + r1; if (ga1 >= M) ga1 = M - 1;
    int gb0 = n0 + r0; if (gb0 >= N) gb0 = N - 1;
    int gb1 = n0 + r1; if (gb1 >= N) gb1 = N - 1;
    const long oa0 = (long)ga0 * K + k80 * 8, oa1 = (long)ga1 * K + k81 * 8;
    const long ob0 = (long)gb0 * K + k80 * 8, ob1 = (long)gb1 * K + k81 * 8;
    for (int ph = 0; ph < 3; ++ph) {
        const f16* Ap = (ph == 2 ? Alo : Ahi) + za;
        const f16* Bp = (ph == 1 ? Blo : Bhi) + zb;
        for (int kt = 0; kt < K; kt += 32) {
            gld16(Ap + oa0 + kt, As + idxu * 8);
            gld16(Ap + oa1 + kt, As + idxu * 8 + 512);
            gld16(Bp + ob0 + kt, Bs + idxu * 8);
            gld16(Bp + ob1 + kt, Bs + idxu * 8 + 512);
            __syncthreads();
            f16x8 af[4], bf[4];
#pragma unroll
            for (int m = 0; m < 4; ++m) af[m] = *(const f16x8*)(As + (wm * 64 + m * 16 + fr) * 32 + kg * 8);
#pragma unroll
            for (int n = 0; n < 4; ++n) bf[n] = *(const f16x8*)(Bs + (wn * 64 + n * 16 + fr) * 32 + kg * 8);
#pragma unroll
            for (int m = 0; m < 4; ++m)
#pragma unroll
                for (int n = 0; n < 4; ++n)
                    acc[m][n] = __builtin_amdgcn_mfma_f32_16x16x32_f16(af[m], bf[n], acc[m][n], 0, 0, 0);
            __syncthreads();
        }
    }
    const int crow = m0 + wm * 64 + (lane >> 4) * 4;
    const int ccol = n0 + wn * 64 + fr;
#pragma unroll
    for (int n = 0; n < 4; ++n) {
        int col = ccol + n * 16;
        if (col >= N) continue;
#pragma unroll
        for (int m = 0; m < 4; ++m) {
#pragma unroll
            for (int q = 0; q < 4; ++q) {
                int row = crow + m * 16 + q;
                if (row < M) C[(long)row * N + col] = acc[m][n][q];
            }
        }
    }
}

// ---------------------------------------------------------------- vocab tile (device fn)
// A = Hs (step-major rows: arow = s*8 + chain); out row = (arow&7)*270 + (arow>>3).
// C[orow] = exp(...), psum[nt][orow] = per-tile row partial sum.
__device__ __forceinline__ void vocab_tile(int mt, int nt, const f16* __restrict__ A,
                                           const f16* __restrict__ Bm, float* __restrict__ C,
                                           float* __restrict__ psum, f16* As, f16* Bs,
                                           float* rpart, int tid) {
    const int M = R_, N = V_, K = H_;
    const int m0 = mt * 128, n0 = nt * 128;
    const int lane = tid & 63, wave = tid >> 6;
    const int wm = wave >> 1, wn = wave & 1;
    const int fr = lane & 15, kg = lane >> 4;
    f32x4 acc[4][4] = {};
    const int idxu = wave * 128;
    const int i0 = idxu + lane, i1 = idxu + 64 + lane;
    const int r0 = i0 >> 2, k80 = i0 & 3;
    const int r1 = i1 >> 2, k81 = i1 & 3;
    int ga0 = m0 + r0; if (ga0 >= M) ga0 = M - 1;
    int ga1 = m0 + r1; if (ga1 >= M) ga1 = M - 1;
    int gb0 = n0 + r0; if (gb0 >= N) gb0 = N - 1;
    int gb1 = n0 + r1; if (gb1 >= N) gb1 = N - 1;
    const f16* pa0 = A + (long)ga0 * K + k80 * 8;
    const f16* pa1 = A + (long)ga1 * K + k81 * 8;
    const f16* pb0 = Bm + (long)gb0 * K + k80 * 8;
    const f16* pb1 = Bm + (long)gb1 * K + k81 * 8;
    for (int kt = 0; kt < K; kt += 32) {
        gld16(pa0 + kt, As + idxu * 8);
        gld16(pa1 + kt, As + idxu * 8 + 512);
        gld16(pb0 + kt, Bs + idxu * 8);
        gld16(pb1 + kt, Bs + idxu * 8 + 512);
        __syncthreads();
        f16x8 af[4], bf[4];
#pragma unroll
        for (int m = 0; m < 4; ++m) af[m] = *(const f16x8*)(As + (wm * 64 + m * 16 + fr) * 32 + kg * 8);
#pragma unroll
        for (int n = 0; n < 4; ++n) bf[n] = *(const f16x8*)(Bs + (wn * 64 + n * 16 + fr) * 32 + kg * 8);
#pragma unroll
        for (int m = 0; m < 4; ++m)
#pragma unroll
            for (int n = 0; n < 4; ++n)
                acc[m][n] = __builtin_amdgcn_mfma_f32_16x16x32_f16(af[m], bf[n], acc[m][n], 0, 0, 0);
        __syncthreads();
    }
    const int crow = m0 + wm * 64 + (lane >> 4) * 4;
    const int ccol = n0 + wn * 64 + fr;
    float rs[4][4];
#pragma unroll
    for (int m = 0; m < 4; ++m)
#pragma unroll
        for (int q = 0; q < 4; ++q) rs[m][q] = 0.f;
#pragma unroll
    for (int n = 0; n < 4; ++n) {
        int col = ccol + n * 16;
        if (col >= N) continue;
#pragma unroll
        for (int m = 0; m < 4; ++m) {
#pragma unroll
            for (int q = 0; q < 4; ++q) {
                int row = crow + m * 16 + q;
                if (row < M) {
                    int orow = (row & 7) * 270 + (row >> 3);
                    float e = __expf(acc[m][n][q]);
                    C[(long)orow * N + col] = e;
                    rs[m][q] += e;
                }
            }
        }
    }
#pragma unroll
    for (int m = 0; m < 4; ++m)
#pragma unroll
        for (int q = 0; q < 4; ++q) {
            float v = rs[m][q];
            v += __shfl_xor(v, 1);
            v += __shfl_xor(v, 2);
            v += __shfl_xor(v, 4);
            v += __shfl_xor(v, 8);
            rs[m][q] = v;
        }
    if ((lane & 15) == 0) {
#pragma unroll
        for (int m = 0; m < 4; ++m)
#pragma unroll
            for (int q = 0; q < 4; ++q)
                rpart[wn * 128 + wm * 64 + (lane >> 4) * 4 + m * 16 + q] = rs[m][q];
    }
    __syncthreads();
    if (tid < 128) {
        int row = m0 + tid;
        if (row < M) {
            int orow = (row & 7) * 270 + (row >> 3);
            psum[(long)nt * M + orow] = rpart[tid] + rpart[128 + tid];
        }
    }
}

// ---------------------------------------------------------------- post-recurrence vocab drain
__global__ __launch_bounds__(256) void k_vocab(const f16* __restrict__ Hs, const f16* __restrict__ emb16,
                                               float* __restrict__ out, float* __restrict__ psum,
                                               int* ctl) {
    __shared__ f16 As[128 * 32];
    __shared__ f16 Bs[128 * 32];
    __shared__ float rpart[256];
    __shared__ int q_s;
    if (threadIdx.x == 0)
        q_s = __hip_atomic_fetch_add(ctl, 1, __ATOMIC_RELAXED, __HIP_MEMORY_SCOPE_AGENT);
    __syncthreads();
    int q = q_s;
    if (q >= NTILE) return;
    vocab_tile(q / VNT, q % VNT, Hs, emb16, out, psum, As, Bs, rpart, threadIdx.x);
}

// ---------------------------------------------------------------- GRU recurrence + prep + vocab workers
__device__ __forceinline__ float fd2(unsigned hv, unsigned wv, float acc) {
#if __has_builtin(__builtin_amdgcn_fdot2)
    return __builtin_amdgcn_fdot2(__builtin_bit_cast(h2, hv), __builtin_bit_cast(h2, wv), acc, false);
#else
    h2 a = __builtin_bit_cast(h2, hv), b = __builtin_bit_cast(h2, wv);
    return acc + (float)a.x * (float)b.x + (float)a.y * (float)b.y;
#endif
}

__global__ __launch_bounds__(256, 1) void k_gru(const float* __restrict__ gi,
                                                const float* __restrict__ whh,
                                                const float* __restrict__ bhh,
                                                ull* hbuf,
                                                f16* __restrict__ Hhi, f16* __restrict__ Hlo,
                                                f16* __restrict__ Hs,
                                                const float* __restrict__ emb, f16* __restrict__ emb16,
                                                const float* __restrict__ enc, f16* __restrict__ ehi,
                                                f16* __restrict__ elo, f16* __restrict__ encT,
                                                float* __restrict__ out, float* __restrict__ psum,
                                                int* ctl) {
    __shared__ ui4v wsvu[9216];               // weights (recurrence) / As+Bs+rpart (workers)
    __shared__ __align__(16) f16 hsf[768];
    __shared__ float part[2][8][32][3];
    __shared__ int q_s;
    const int tid = threadIdx.x;
    int* prog = ctl + 256;
    if (blockIdx.x >= 192) {
        // ---------- prep on idle CUs ----------
        const long pt = (long)(blockIdx.x - 192) * 256 + tid;
        const long n4 = (long)V_ * H_ / 4;
        for (long i = pt; i < n4; i += 64 * 256) {
            f32x4 v = ((const f32x4*)emb)[i];
            f16x4v r = {(f16)v.x, (f16)v.y, (f16)v.z, (f16)v.w};
            // agent-scope atomic store -> visible at MALL for in-kernel workers
            __hip_atomic_store((ull*)emb16 + i, __builtin_bit_cast(ull, r),
                               __ATOMIC_RELAXED, __HIP_MEMORY_SCOPE_AGENT);
        }
        const long n4e = (long)B_ * S_ * H_ / 4;
        for (long i = pt; i < n4e; i += 64 * 256) {
            f32x4 v = ((const f32x4*)enc)[i];
            f16 h0 = (f16)v.x, h1 = (f16)v.y, h2v = (f16)v.z, h3 = (f16)v.w;
            f16x4v hv = {h0, h1, h2v, h3};
            ((f16x4v*)ehi)[i] = hv;
            f16x4v lv = {(f16)(v.x - (float)h0), (f16)(v.y - (float)h1),
                         (f16)(v.z - (float)h2v), (f16)(v.w - (float)h3)};
            ((f16x4v*)elo)[i] = lv;
        }
        // encT via LDS-tiled transpose (64x64 f32 tile, pad 65)
        float* tl = (float*)wsvu;
        for (int t = blockIdx.x - 192; t < 8 * 8 * 12; t += 64) {
            int ht = t % 12, st = (t / 12) % 8, bb = t / 96;
            __syncthreads();
#pragma unroll
            for (int k = 0; k < 16; ++k) {
                int i = tid + k * 256;
                int sl = i >> 6, hl = i & 63;
                tl[sl * 65 + hl] = enc[((long)bb * S_ + st * 64 + sl) * H_ + ht * 64 + hl];
            }
            __syncthreads();
#pragma unroll
            for (int k = 0; k < 16; ++k) {
                int i = tid + k * 256;
                int hl = i >> 6, sl = i & 63;
                encT[((long)bb * H_ + ht * 64 + hl) * S_ + st * 64 + sl] = (f16)tl[sl * 65 + hl];
            }
        }
        // signal prep done; wait for all 64 prep blocks (emb16 complete)
        if (tid == 0) {
            asm volatile("s_waitcnt vmcnt(0)" ::: "memory");
            __hip_atomic_fetch_add(ctl + 32, 1, __ATOMIC_RELAXED, __HIP_MEMORY_SCOPE_AGENT);
            while (__hip_atomic_load(ctl + 32, __ATOMIC_RELAXED, __HIP_MEMORY_SCOPE_AGENT) < 64)
                __builtin_amdgcn_s_sleep(8);
            __builtin_amdgcn_fence(__ATOMIC_ACQUIRE, "agent");
        }
        __syncthreads();
        // ---------- vocab worker loop (while recurrence running) ----------
        f16* Asp = (f16*)wsvu;
        f16* Bsp = Asp + 128 * 32;
        float* rpp = (float*)(Bsp + 128 * 32);
        for (;;) {
            if (tid == 0) {
                int q = -1;
                if (__hip_atomic_load(ctl + 64, __ATOMIC_RELAXED, __HIP_MEMORY_SCOPE_AGENT) < 192) {
                    q = __hip_atomic_fetch_add(ctl, 1, __ATOMIC_RELAXED, __HIP_MEMORY_SCOPE_AGENT);
                    if (q >= NTILE) q = -1;
                }
                if (q >= 0) {
                    int mt = q / VNT;
                    int need = ((mt * 128 + 127) >> 3) + 1;   // steps required of every block
                    for (;;) {
                        int mn = 1 << 30;
                        for (int i2 = 0; i2 < 192; ++i2) {
                            int v = __hip_atomic_load(prog + i2, __ATOMIC_RELAXED, __HIP_MEMORY_SCOPE_AGENT);
                            mn = v < mn ? v : mn;
                        }
                        if (mn >= need) break;
                        __builtin_amdgcn_s_sleep(16);
                    }
                    __builtin_amdgcn_fence(__ATOMIC_ACQUIRE, "agent");
                }
                q_s = q;
            }
            __syncthreads();
            int q = q_s;
            if (q < 0) break;
            vocab_tile(q / VNT, q % VNT, Hs, emb16, out, psum, Asp, Bsp, rpp, tid);
            __syncthreads();
        }
        return;
    }
    // ---------- recurrence ----------
    const int chain = blockIdx.x / 24;
    const int blk = blockIdx.x % 24;
    const int u0 = blk * 32;
    for (int idx = tid; idx < 9216; idx += 256) {
        int uu = idx & 31, k8 = (idx >> 5) % 96, g = idx / (96 * 32);
        const float* src = whh + (long)(g * H_ + u0 + uu) * H_ + k8 * 8;
        f32x4 a = *(const f32x4*)src;
        f32x4 b2 = *(const f32x4*)(src + 4);
        f16x8 pk = {(f16)a.x, (f16)a.y, (f16)a.z, (f16)a.w,
                    (f16)b2.x, (f16)b2.y, (f16)b2.z, (f16)b2.w};
        wsvu[idx] = __builtin_bit_cast(ui4v, pk);
    }
    float b_r = 0.f, b_z = 0.f, b_n = 0.f;
    if (tid < 32) {
        int c = u0 + tid;
        b_r = bhh[c];
        b_z = bhh[H_ + c];
        b_n = bhh[2 * H_ + c];
    }
    __syncthreads();
    const int u = tid & 31, q = tid >> 5, lane = tid & 63;
    const int pw = (tid >> 6) * 192 + lane;
    ui4v wreg[3][12];
#pragma unroll
    for (int g = 0; g < 3; ++g)
#pragma unroll
        for (int i = 0; i < 12; ++i)
            wreg[g][i] = wsvu[(g * 96 + q * 12 + i) * 32 + u];
    ull* base = hbuf + (long)chain * 1536;
    const bool fin = (tid < 32);
    float g0 = 0.f, g1 = 0.f, g2v = 0.f;
    if (fin) {
        const float* gp = gi + (long)chain * 270 * H3;
        int c = u0 + tid;
        g0 = gp[c];
        g1 = gp[H_ + c];
        g2v = gp[2 * H_ + c];
    }
    for (int s = 0; s < 270; ++s) {
        const ull* rb = base + (s & 1) * 768;
        ull* wb = base + ((s + 1) & 1) * 768;
        const unsigned want = (unsigned)s;
        ull v0, v1, v2, vh = 0;
        for (;;) {
            v0 = __hip_atomic_load(rb + pw, __ATOMIC_RELAXED, __HIP_MEMORY_SCOPE_AGENT);
            v1 = __hip_atomic_load(rb + pw + 64, __ATOMIC_RELAXED, __HIP_MEMORY_SCOPE_AGENT);
            v2 = __hip_atomic_load(rb + pw + 128, __ATOMIC_RELAXED, __HIP_MEMORY_SCOPE_AGENT);
            bool ok = ((unsigned)(v0 >> 32) == want) & ((unsigned)(v1 >> 32) == want) &
                      ((unsigned)(v2 >> 32) == want);
            if (fin) {
                vh = __hip_atomic_load(rb + u0 + tid, __ATOMIC_RELAXED, __HIP_MEMORY_SCOPE_AGENT);
                ok &= ((unsigned)(vh >> 32) == want);
            }
            if (ok) break;
        }
        hsf[pw] = (f16)__uint_as_float((unsigned)v0);
        hsf[pw + 64] = (f16)__uint_as_float((unsigned)v1);
        hsf[pw + 128] = (f16)__uint_as_float((unsigned)v2);
        __builtin_amdgcn_wave_barrier();
        float ar = 0.f, az = 0.f, an = 0.f;
#pragma unroll
        for (int i = 0; i < 12; ++i) {
            ui4v hv = *(const ui4v*)(&hsf[(q * 12 + i) * 8]);
            ui4v wr = wreg[0][i], wz = wreg[1][i], wn = wreg[2][i];
            ar = fd2(hv.x, wr.x, ar); ar = fd2(hv.y, wr.y, ar);
            ar = fd2(hv.z, wr.z, ar); ar = fd2(hv.w, wr.w, ar);
            az = fd2(hv.x, wz.x, az); az = fd2(hv.y, wz.y, az);
            az = fd2(hv.z, wz.z, az); az = fd2(hv.w, wz.w, az);
            an = fd2(hv.x, wn.x, an); an = fd2(hv.y, wn.y, an);
            an = fd2(hv.z, wn.z, an); an = fd2(hv.w, wn.w, an);
        }
        const int par = s & 1;
        part[par][q][u][0] = ar;
        part[par][q][u][1] = az;
        part[par][q][u][2] = an;
        __syncthreads();
        if (fin) {
            float gr = b_r, gz = b_z, gn = b_n;
#pragma unroll
            for (int qq = 0; qq < 8; ++qq) {
                gr += part[par][qq][tid][0];
                gz += part[par][qq][tid][1];
                gn += part[par][qq][tid][2];
            }
            float hold = __uint_as_float((unsigned)vh);
            float rg = 1.f / (1.f + __expf(-(g0 + gr)));
            float zg = 1.f / (1.f + __expf(-(g1 + gz)));
            float xa = g2v + rg * gn;
            float e2 = __expf(-2.f * xa);
            float ng = (1.f - e2) / (1.f + e2);
            float hnew = (1.f - zg) * ng + zg * hold;
            int c = u0 + tid;
            ull wvv = ((ull)(unsigned)(s + 1) << 32) | (ull)__float_as_uint(hnew);
            __hip_atomic_store(wb + c, wvv, __ATOMIC_RELAXED, __HIP_MEMORY_SCOPE_AGENT);
            long row = (long)chain * 270 + s;
            f16 h16 = (f16)hnew;
            Hhi[row * H_ + c] = h16;
            Hlo[row * H_ + c] = (f16)(hnew - (float)h16);
            // step-major copy for in-kernel vocab workers (agent-visible)
            unsigned hb = (unsigned)__builtin_bit_cast(unsigned short, h16);
            unsigned up2 = (unsigned)__shfl_down((int)hb, 1);
            if (!(tid & 1)) {
                long sidx = ((long)s * 8 + chain) * H_ + c;
                __hip_atomic_store((unsigned*)Hs + (sidx >> 1), hb | (up2 << 16),
                                   __ATOMIC_RELAXED, __HIP_MEMORY_SCOPE_AGENT);
            }
            asm volatile("s_waitcnt vmcnt(0)" ::: "memory");
            if (tid == 0)
                __hip_atomic_store(prog + chain * 24 + blk, s + 1,
                                   __ATOMIC_RELAXED, __HIP_MEMORY_SCOPE_AGENT);
            if (s < 269) {
                const float* gp = gi + ((long)chain * 270 + s + 1) * H3;
                g0 = gp[c];
                g1 = gp[H_ + c];
                g2v = gp[2 * H_ + c];
            }
        }
    }
    if (tid == 0)
        __hip_atomic_fetch_add(ctl + 64, 1, __ATOMIC_RELAXED, __HIP_MEMORY_SCOPE_AGENT);
}

// ---------------------------------------------------------------- attention softmax
__global__ __launch_bounds__(256) void k_attn_softmax(const float* __restrict__ lg,
                                                      const int* __restrict__ x, f16* __restrict__ ah) {
    __shared__ float red[256];
    int r = blockIdx.x, tid = threadIdx.x;
    int b = r / 270;
    const float* lr = lg + (long)r * S_;
    const int* xb = x + (long)b * S_;
    float v0 = lr[tid];
    if (xb[tid] == 0) v0 = -1e9f;
    float v1 = lr[tid + 256];
    if (xb[tid + 256] == 0) v1 = -1e9f;
    red[tid] = fmaxf(v0, v1);
    __syncthreads();
    for (int o = 128; o > 0; o >>= 1) {
        if (tid < o) red[tid] = fmaxf(red[tid], red[tid + o]);
        __syncthreads();
    }
    float m = red[0];
    __syncthreads();
    float e0 = __expf(v0 - m), e1 = __expf(v1 - m);
    red[tid] = e0 + e1;
    __syncthreads();
    for (int o = 128; o > 0; o >>= 1) {
        if (tid < o) red[tid] += red[tid + o];
        __syncthreads();
    }
    float inv = 1.f / red[0];
    ah[(long)r * S_ + tid] = (f16)(e0 * inv);
    ah[(long)r * S_ + tid + 256] = (f16)(e1 * inv);
}

// ---------------------------------------------------------------- p_gen
__global__ __launch_bounds__(256) void k_pgen(const f16* __restrict__ Wall, const f16* __restrict__ Hhi,
                                              const f16* __restrict__ Hlo, const float* __restrict__ ctx,
                                              const float* __restrict__ wg, const float* __restrict__ wgb,
                                              float* __restrict__ pg) {
    __shared__ float red[256];
    int r = blockIdx.x, tid = threadIdx.x;
    float a = 0.f;
    for (int i = tid; i < H_; i += 256) {
        a += (float)Wall[(long)r * H_ + i] * wg[i];
        a += ((float)Hhi[(long)r * H_ + i] + (float)Hlo[(long)r * H_ + i]) * wg[H_ + i];
        a += ctx[(long)r * H_ + i] * wg[2 * H_ + i];
    }
    red[tid] = a;
    __syncthreads();
    for (int o = 128; o > 0; o >>= 1) {
        if (tid < o) red[tid] += red[tid + o];
        __syncthreads();
    }
    if (tid == 0) pg[r] = 1.f / (1.f + expf(-(red[0] + wgb[0])));
}

// ---------------------------------------------------------------- fused rinv + finalize + scatter
__global__ __launch_bounds__(256, 1) void k_fin3(float* __restrict__ out,
                                                 const float* __restrict__ psum,
                                                 const float* __restrict__ pg,
                                                 const f16* __restrict__ ah,
                                                 const int* __restrict__ x) {
    __shared__ float row[V_];
    __shared__ float red[256];
    const int r = blockIdx.x, tid = threadIdx.x;
    const int b = r / 270;
    float s = 0.f;
    for (int i = tid; i < VNT; i += 256) s += psum[(long)i * R_ + r];
    red[tid] = s;
    __syncthreads();
    for (int o = 128; o > 0; o >>= 1) {
        if (tid < o) red[tid] += red[tid + o];
        __syncthreads();
    }
    const float pgv = pg[r];
    const float scale = pgv / red[0];
    float* orow = out + (long)r * V_;
    for (int i = tid; i < V_ / 4; i += 256) {
        f32x4 v = ((const f32x4*)orow)[i];
        v.x *= scale;
        v.y *= scale;
        v.z *= scale;
        v.w *= scale;
        ((f32x4*)row)[i] = v;
    }
    __syncthreads();
    const float om = 1.f - pgv;
    for (int s2 = tid; s2 < S_; s2 += 256) {
        int xv = x[(long)b * S_ + s2];
        if (xv != 0) {
            float a = (float)ah[(long)r * S_ + s2];
            if (a != 0.f) atomicAdd(&row[xv], om * a);
        }
    }
    __syncthreads();
    for (int i = tid; i < V_ / 4; i += 256)
        ((f32x4*)orow)[i] = ((const f32x4*)row)[i];
}

// ---------------------------------------------------------------- host
extern "C" void kernel_launch(void* const* d_in, const int* in_sizes, int n_in, void* d_out,
                              int out_size, void* d_ws, size_t ws_size, hipStream_t stream) {
    (void)in_sizes; (void)n_in; (void)out_size; (void)ws_size;
    const int* x = (const int*)d_in[0];
    const float* dec = (const float*)d_in[1];
    const float* enc = (const float*)d_in[2];
    const float* hid = (const float*)d_in[3];
    const int* tea = (const int*)d_in[4];
    const float* emb = (const float*)d_in[6];
    const float* wih = (const float*)d_in[7];
    const float* whh = (const float*)d_in[8];
    const float* bih = (const float*)d_in[9];
    const float* bhh = (const float*)d_in[10];
    const float* wgw = (const float*)d_in[11];
    const float* wgb = (const float*)d_in[12];
    float* out = (float*)d_out;

    char* w = (char*)d_ws;
    size_t off = 0;
    auto alloc = [&](size_t bytes) {
        void* p = w + off;
        off = (off + bytes + 255) & ~(size_t)255;
        return p;
    };
    int* ctl = (int*)alloc(CTL_INTS * 4);           // queue/prepdone/grudone/prog
    ull* hbuf = (ull*)alloc(8 * 1536 * 8);          // seq-tagged h exchange
    f16* Wall = (f16*)alloc((size_t)R_ * H_ * 2);
    f16* wih16 = (f16*)alloc((size_t)H3 * H_ * 2);
    float* giA = (float*)alloc((size_t)R_ * H3 * 4);
    f16* Hhi = (f16*)alloc((size_t)R_ * H_ * 2);
    f16* Hlo = (f16*)alloc((size_t)R_ * H_ * 2);
    f16* Hs = (f16*)alloc((size_t)R_ * H_ * 2);     // step-major copy
    f16* emb16 = (f16*)alloc((size_t)V_ * H_ * 2);
    f16* ehi = (f16*)alloc((size_t)B_ * S_ * H_ * 2);
    f16* elo = (f16*)alloc((size_t)B_ * S_ * H_ * 2);
    f16* encT = (f16*)alloc((size_t)B_ * H_ * S_ * 2);
    float* lgH = (float*)alloc((size_t)R_ * S_ * 4);
    f16* ah = (f16*)alloc((size_t)R_ * S_ * 2);
    float* ctx = (float*)alloc((size_t)R_ * H_ * 4);
    float* pg = (float*)alloc(R_ * 4);
    float* psum = (float*)alloc((size_t)VNT * R_ * 4);

    const int nZ = CTL_INTS + 8 * 1536 * 2;         // ctl + hbuf (contiguous)
    k_zero<<<(nZ + 255) / 256, 256, 0, stream>>>(ctl, nZ);
    k_cast<<<512, 256, 0, stream>>>(wih, wih16, (long)H3 * H_);
    k_build_wall<<<R_, 256, 0, stream>>>(emb, dec, tea, Wall);
    k_init_h<<<24, 256, 0, stream>>>(hid, hbuf);

    // gi = W_all @ w_ih^T + b_ih
    {
        dim3 g(H3 / 128, (R_ + 127) / 128, 1);
        k_gemm<1><<<g, 256, 0, stream>>>(Wall, wih16, giA, bih, R_, H3, H_, 0, 0, 0);
    }
    // recurrence (0-191) + prep & in-flight vocab workers (192-255)
    k_gru<<<256, 256, 0, stream>>>(giA, whh, bhh, hbuf, Hhi, Hlo, Hs,
                                   emb, emb16, enc, ehi, elo, encT, out, psum, ctl);

    // attention logits (merged hi/lo)
    {
        dim3 g(S_ / 128, 3, 8);
        k_attn3<<<g, 256, 0, stream>>>(Hhi, Hlo, ehi, elo, lgH, 270, S_, H_,
                                       270L * H_, (long)S_ * H_, 270L * S_);
    }
    k_attn_softmax<<<R_, 256, 0, stream>>>(lgH, x, ah);
    {
        dim3 g(H_ / 128, 3, 8);
        k_gemm<0><<<g, 256, 0, stream>>>(ah, encT, ctx, nullptr, 270, H_, S_, 270L * S_, (long)H_ * S_, 270L * H_);
    }
    k_pgen<<<R_, 256, 0, stream>>>(Wall, Hhi, Hlo, ctx, wgw, wgb, pg);

    // drain remaining vocab tiles at full width
    k_vocab<<<NTILE, 256, 0, stream>>>(Hs, emb16, out, psum, ctl);
    // fused rinv + finalize + pointer-scatter
    k_fin3<<<R_, 256, 0, stream>>>(out, psum, pg, ah, x);
}

// Round 14
// 1137.716 us; speedup vs baseline: 1.0761x; 1.0761x over previous
//
#include <hip/hip_runtime.h>
#include <hip/hip_bf16.h>

typedef _Float16 f16;
typedef _Float16 f16x8 __attribute__((ext_vector_type(8)));
typedef _Float16 f16x4v __attribute__((ext_vector_type(4)));
typedef _Float16 h2 __attribute__((ext_vector_type(2)));
typedef float f32x4 __attribute__((ext_vector_type(4)));
typedef unsigned ui4v __attribute__((ext_vector_type(4)));
typedef unsigned long long ull;

#define B_ 8
#define S_ 512
#define H_ 768
#define V_ 35004
#define J_ 30
#define K_ 9
#define R_ 2160          // out rows, r = b*270 + j*9 + t
#define H3 2304
#define VMT 17           // vocab M tiles
#define VNT 274          // vocab N tiles
#define CASTB 864        // extra blocks in k_prep for wih cast

// ---------------------------------------------------------------- prep kernels

// rows < R_: build W_all; rows >= R_: cast wih -> f16
__global__ void k_prep(const float* __restrict__ emb, const float* __restrict__ dec,
                       const int* __restrict__ teacher, f16* __restrict__ Wall,
                       const float* __restrict__ wih, f16* __restrict__ wih16) {
    int r = blockIdx.x;
    if (r < R_) {
        int b = r / 270, s = r % 270, j = s / 9, t = s % 9;
        const float* src = (t == 0) ? dec + ((long)b * J_ + j) * H_
                                    : emb + (long)teacher[((long)b * J_ + j) * K_ + (t - 1)] * H_;
        f16* dst = Wall + (long)r * H_;
        for (int c = threadIdx.x; c < H_; c += 256) dst[c] = (f16)src[c];
    } else {
        const long n = (long)H3 * H_;
        for (long i = (long)(r - R_) * 256 + threadIdx.x; i < n; i += (long)CASTB * 256)
            wih16[i] = (f16)wih[i];
    }
}

// h exchange word: {seq:32 | f32 bits:32}; chain-major [chain][parity][768].
// Writes BOTH parities every call (replay-deterministic, replaces k_zero).
__global__ void k_init_h(const float* __restrict__ hidden, ull* __restrict__ hbuf) {
    int i = blockIdx.x * 256 + threadIdx.x;
    if (i < B_ * H_) {
        int b = i / H_, u = i % H_;
        hbuf[(long)b * 1536 + u] = (ull)__float_as_uint(hidden[i]);  // seq 0, parity 0
        hbuf[(long)b * 1536 + 768 + u] = 0;                          // parity 1 cleared
    }
}

// ---------------------------------------------------------------- shared GEMM helpers
typedef const __attribute__((address_space(1))) unsigned GASU;
typedef __attribute__((address_space(3))) unsigned LASU;
__device__ __forceinline__ void gld16(const f16* g, f16* l) {
    __builtin_amdgcn_global_load_lds((GASU*)g, (LASU*)l, 16, 0, 0);
}

// ---------------------------------------------------------------- f16 MFMA GEMM (m97 structure)
// C[M,N] = A[M,K] @ B[N,K]^T ; MODE 0: store, 1: store + bias[col]
template <int MODE>
__global__ __launch_bounds__(256) void k_gemm(const f16* __restrict__ A, const f16* __restrict__ Bm,
                                              float* __restrict__ C, const float* __restrict__ bias,
                                              int M, int N, int K, long sA, long sB, long sC) {
    A += (long)blockIdx.z * sA;
    Bm += (long)blockIdx.z * sB;
    C += (long)blockIdx.z * sC;
    const int m0 = blockIdx.y * 128, n0 = blockIdx.x * 128;
    __shared__ f16 As[128 * 32];
    __shared__ f16 Bs[128 * 32];
    const int tid = threadIdx.x, lane = tid & 63, wave = tid >> 6;
    const int wm = wave >> 1, wn = wave & 1;
    const int fr = lane & 15, kg = lane >> 4;
    f32x4 acc[4][4] = {};
    const int idxu = wave * 128;
    const int i0 = idxu + lane, i1 = idxu + 64 + lane;
    const int r0 = i0 >> 2, k80 = i0 & 3;
    const int r1 = i1 >> 2, k81 = i1 & 3;
    int ga0 = m0 + r0; if (ga0 >= M) ga0 = M - 1;
    int ga1 = m0 + r1; if (ga1 >= M) ga1 = M - 1;
    int gb0 = n0 + r0; if (gb0 >= N) gb0 = N - 1;
    int gb1 = n0 + r1; if (gb1 >= N) gb1 = N - 1;
    const f16* pa0 = A + (long)ga0 * K + k80 * 8;
    const f16* pa1 = A + (long)ga1 * K + k81 * 8;
    const f16* pb0 = Bm + (long)gb0 * K + k80 * 8;
    const f16* pb1 = Bm + (long)gb1 * K + k81 * 8;
    for (int kt = 0; kt < K; kt += 32) {
        gld16(pa0 + kt, As + idxu * 8);
        gld16(pa1 + kt, As + idxu * 8 + 512);
        gld16(pb0 + kt, Bs + idxu * 8);
        gld16(pb1 + kt, Bs + idxu * 8 + 512);
        __syncthreads();
        f16x8 af[4], bf[4];
#pragma unroll
        for (int m = 0; m < 4; ++m) af[m] = *(const f16x8*)(As + (wm * 64 + m * 16 + fr) * 32 + kg * 8);
#pragma unroll
        for (int n = 0; n < 4; ++n) bf[n] = *(const f16x8*)(Bs + (wn * 64 + n * 16 + fr) * 32 + kg * 8);
#pragma unroll
        for (int m = 0; m < 4; ++m)
#pragma unroll
            for (int n = 0; n < 4; ++n)
                acc[m][n] = __builtin_amdgcn_mfma_f32_16x16x32_f16(af[m], bf[n], acc[m][n], 0, 0, 0);
        __syncthreads();
    }
    const int crow = m0 + wm * 64 + (lane >> 4) * 4;
    const int ccol = n0 + wn * 64 + fr;
#pragma unroll
    for (int n = 0; n < 4; ++n) {
        int col = ccol + n * 16;
        if (col >= N) continue;
        float bv = (MODE == 1) ? bias[col] : 0.f;
#pragma unroll
        for (int m = 0; m < 4; ++m) {
#pragma unroll
            for (int q = 0; q < 4; ++q) {
                int row = crow + m * 16 + q;
                if (row < M) C[(long)row * N + col] = acc[m][n][q] + bv;
            }
        }
    }
}

// ---------------------------------------------------------------- merged hi/lo attention logits
__global__ __launch_bounds__(256) void k_attn3(const f16* __restrict__ Ahi, const f16* __restrict__ Alo,
                                               const f16* __restrict__ Bhi, const f16* __restrict__ Blo,
                                               float* __restrict__ C, int M, int N, int K,
                                               long sA, long sB, long sC) {
    const long za = (long)blockIdx.z * sA, zb = (long)blockIdx.z * sB;
    C += (long)blockIdx.z * sC;
    const int m0 = blockIdx.y * 128, n0 = blockIdx.x * 128;
    __shared__ f16 As[128 * 32];
    __shared__ f16 Bs[128 * 32];
    const int tid = threadIdx.x, lane = tid & 63, wave = tid >> 6;
    const int wm = wave >> 1, wn = wave & 1;
    const int fr = lane & 15, kg = lane >> 4;
    f32x4 acc[4][4] = {};
    const int idxu = wave * 128;
    const int i0 = idxu + lane, i1 = idxu + 64 + lane;
    const int r0 = i0 >> 2, k80 = i0 & 3;
    const int r1 = i1 >> 2, k81 = i1 & 3;
    int ga0 = m0 + r0; if (ga0 >= M) ga0 = M - 1;
    int ga1 = m0 + r1; if (ga1 >= M) ga1 = M - 1;
    int gb0 = n0 + r0; if (gb0 >= N) gb0 = N - 1;
    int gb1 = n0 + r1; if (gb1 >= N) gb1 = N - 1;
    const long oa0 = (long)ga0 * K + k80 * 8, oa1 = (long)ga1 * K + k81 * 8;
    const long ob0 = (long)gb0 * K + k80 * 8, ob1 = (long)gb1 * K + k81 * 8;
    for (int ph = 0; ph < 3; ++ph) {
        const f16* Ap = (ph == 2 ? Alo : Ahi) + za;
        const f16* Bp = (ph == 1 ? Blo : Bhi) + zb;
        for (int kt = 0; kt < K; kt += 32) {
            gld16(Ap + oa0 + kt, As + idxu * 8);
            gld16(Ap + oa1 + kt, As + idxu * 8 + 512);
            gld16(Bp + ob0 + kt, Bs + idxu * 8);
            gld16(Bp + ob1 + kt, Bs + idxu * 8 + 512);
            __syncthreads();
            f16x8 af[4], bf[4];
#pragma unroll
            for (int m = 0; m < 4; ++m) af[m] = *(const f16x8*)(As + (wm * 64 + m * 16 + fr) * 32 + kg * 8);
#pragma unroll
            for (int n = 0; n < 4; ++n) bf[n] = *(const f16x8*)(Bs + (wn * 64 + n * 16 + fr) * 32 + kg * 8);
#pragma unroll
            for (int m = 0; m < 4; ++m)
#pragma unroll
                for (int n = 0; n < 4; ++n)
                    acc[m][n] = __builtin_amdgcn_mfma_f32_16x16x32_f16(af[m], bf[n], acc[m][n], 0, 0, 0);
            __syncthreads();
        }
    }
    const int crow = m0 + wm * 64 + (lane >> 4) * 4;
    const int ccol = n0 + wn * 64 + fr;
#pragma unroll
    for (int n = 0; n < 4; ++n) {
        int col = ccol + n * 16;
        if (col >= N) continue;
#pragma unroll
        for (int m = 0; m < 4; ++m) {
#pragma unroll
            for (int q = 0; q < 4; ++q) {
                int row = crow + m * 16 + q;
                if (row < M) C[(long)row * N + col] = acc[m][n][q];
            }
        }
    }
}

// ---------------------------------------------------------------- vocab GEMM: out=exp(Hhi@emb^T)+psum
__global__ __launch_bounds__(256) void k_vocab(const f16* __restrict__ A, const f16* __restrict__ Bm,
                                               float* __restrict__ C, float* __restrict__ psum) {
    const int M = R_, N = V_, K = H_;
    const int nwg = VMT * VNT;
    int lin = blockIdx.x;
    int q8 = nwg / 8, r8 = nwg % 8;
    int xcd = lin & 7, idx = lin >> 3;
    int newlin = (xcd < r8) ? xcd * (q8 + 1) + idx : r8 * (q8 + 1) + (xcd - r8) * q8 + idx;
    int mt = newlin % VMT, nt = newlin / VMT;
    const int m0 = mt * 128, n0 = nt * 128;
    __shared__ f16 As[128 * 32];
    __shared__ f16 Bs[128 * 32];
    __shared__ float rpart[2][128];
    const int tid = threadIdx.x, lane = tid & 63, wave = tid >> 6;
    const int wm = wave >> 1, wn = wave & 1;
    const int fr = lane & 15, kg = lane >> 4;
    f32x4 acc[4][4] = {};
    const int idxu = wave * 128;
    const int i0 = idxu + lane, i1 = idxu + 64 + lane;
    const int r0 = i0 >> 2, k80 = i0 & 3;
    const int r1 = i1 >> 2, k81 = i1 & 3;
    int ga0 = m0 + r0; if (ga0 >= M) ga0 = M - 1;
    int ga1 = m0 + r1; if (ga1 >= M) ga1 = M - 1;
    int gb0 = n0 + r0; if (gb0 >= N) gb0 = N - 1;
    int gb1 = n0 + r1; if (gb1 >= N) gb1 = N - 1;
    const f16* pa0 = A + (long)ga0 * K + k80 * 8;
    const f16* pa1 = A + (long)ga1 * K + k81 * 8;
    const f16* pb0 = Bm + (long)gb0 * K + k80 * 8;
    const f16* pb1 = Bm + (long)gb1 * K + k81 * 8;
    for (int kt = 0; kt < K; kt += 32) {
        gld16(pa0 + kt, As + idxu * 8);
        gld16(pa1 + kt, As + idxu * 8 + 512);
        gld16(pb0 + kt, Bs + idxu * 8);
        gld16(pb1 + kt, Bs + idxu * 8 + 512);
        __syncthreads();
        f16x8 af[4], bf[4];
#pragma unroll
        for (int m = 0; m < 4; ++m) af[m] = *(const f16x8*)(As + (wm * 64 + m * 16 + fr) * 32 + kg * 8);
#pragma unroll
        for (int n = 0; n < 4; ++n) bf[n] = *(const f16x8*)(Bs + (wn * 64 + n * 16 + fr) * 32 + kg * 8);
#pragma unroll
        for (int m = 0; m < 4; ++m)
#pragma unroll
            for (int n = 0; n < 4; ++n)
                acc[m][n] = __builtin_amdgcn_mfma_f32_16x16x32_f16(af[m], bf[n], acc[m][n], 0, 0, 0);
        __syncthreads();
    }
    const int crow = m0 + wm * 64 + (lane >> 4) * 4;
    const int ccol = n0 + wn * 64 + fr;
    float rs[4][4];
#pragma unroll
    for (int m = 0; m < 4; ++m)
#pragma unroll
        for (int q = 0; q < 4; ++q) rs[m][q] = 0.f;
#pragma unroll
    for (int n = 0; n < 4; ++n) {
        int col = ccol + n * 16;
        if (col >= N) continue;
#pragma unroll
        for (int m = 0; m < 4; ++m) {
#pragma unroll
            for (int q = 0; q < 4; ++q) {
                int row = crow + m * 16 + q;
                if (row < M) {
                    float e = __expf(acc[m][n][q]);
                    C[(long)row * N + col] = e;
                    rs[m][q] += e;
                }
            }
        }
    }
#pragma unroll
    for (int m = 0; m < 4; ++m)
#pragma unroll
        for (int q = 0; q < 4; ++q) {
            float v = rs[m][q];
            v += __shfl_xor(v, 1);
            v += __shfl_xor(v, 2);
            v += __shfl_xor(v, 4);
            v += __shfl_xor(v, 8);
            rs[m][q] = v;
        }
    if ((lane & 15) == 0) {
#pragma unroll
        for (int m = 0; m < 4; ++m)
#pragma unroll
            for (int q = 0; q < 4; ++q)
                rpart[wn][wm * 64 + (lane >> 4) * 4 + m * 16 + q] = rs[m][q];
    }
    __syncthreads();
    if (tid < 128) {
        int row = m0 + tid;
        if (row < M) psum[(long)nt * M + row] = rpart[0][tid] + rpart[1][tid];
    }
}

// ---------------------------------------------------------------- GRU recurrence + hidden preps
__device__ __forceinline__ float fd2(unsigned hv, unsigned wv, float acc) {
#if __has_builtin(__builtin_amdgcn_fdot2)
    return __builtin_amdgcn_fdot2(__builtin_bit_cast(h2, hv), __builtin_bit_cast(h2, wv), acc, false);
#else
    h2 a = __builtin_bit_cast(h2, hv), b = __builtin_bit_cast(h2, wv);
    return acc + (float)a.x * (float)b.x + (float)a.y * (float)b.y;
#endif
}

__global__ __launch_bounds__(256, 1) void k_gru(const float* __restrict__ gi,
                                                const float* __restrict__ whh,
                                                const float* __restrict__ bhh,
                                                ull* hbuf,
                                                f16* __restrict__ Hhi, f16* __restrict__ Hlo,
                                                const float* __restrict__ emb, f16* __restrict__ emb16,
                                                const float* __restrict__ enc, f16* __restrict__ ehi,
                                                f16* __restrict__ elo, f16* __restrict__ encT) {
    __shared__ ui4v wsvu[9216];               // weights (recurrence) / transpose tile (prep)
    __shared__ __align__(16) f16 hsf[768];
    __shared__ float part[2][8][33][3];       // [parity][octant][unit(pad 33)][gate]
    const int tid = threadIdx.x;
    if (blockIdx.x >= 192) {
        // ---------- hidden prep on idle CUs ----------
        const long pt = (long)(blockIdx.x - 192) * 256 + tid;
        const long n4 = (long)V_ * H_ / 4;
        for (long i = pt; i < n4; i += 64 * 256) {
            f32x4 v = ((const f32x4*)emb)[i];
            f16x4v r = {(f16)v.x, (f16)v.y, (f16)v.z, (f16)v.w};
            ((f16x4v*)emb16)[i] = r;
        }
        const long n4e = (long)B_ * S_ * H_ / 4;
        for (long i = pt; i < n4e; i += 64 * 256) {
            f32x4 v = ((const f32x4*)enc)[i];
            f16 h0 = (f16)v.x, h1 = (f16)v.y, h2v = (f16)v.z, h3 = (f16)v.w;
            f16x4v hv = {h0, h1, h2v, h3};
            ((f16x4v*)ehi)[i] = hv;
            f16x4v lv = {(f16)(v.x - (float)h0), (f16)(v.y - (float)h1),
                         (f16)(v.z - (float)h2v), (f16)(v.w - (float)h3)};
            ((f16x4v*)elo)[i] = lv;
        }
        // encT via LDS-tiled transpose (64x64 f32 tile, pad 65)
        float* tl = (float*)wsvu;
        for (int t = blockIdx.x - 192; t < 8 * 8 * 12; t += 64) {
            int ht = t % 12, st = (t / 12) % 8, bb = t / 96;
            __syncthreads();
#pragma unroll
            for (int k = 0; k < 16; ++k) {
                int i = tid + k * 256;
                int sl = i >> 6, hl = i & 63;
                tl[sl * 65 + hl] = enc[((long)bb * S_ + st * 64 + sl) * H_ + ht * 64 + hl];
            }
            __syncthreads();
#pragma unroll
            for (int k = 0; k < 16; ++k) {
                int i = tid + k * 256;
                int hl = i >> 6, sl = i & 63;
                encT[((long)bb * H_ + ht * 64 + hl) * S_ + st * 64 + sl] = (f16)tl[sl * 65 + hl];
            }
        }
        return;
    }
    // ---------- recurrence ----------
    const int chain = blockIdx.x / 24;
    const int blk = blockIdx.x % 24;
    const int u0 = blk * 32;
    for (int idx = tid; idx < 9216; idx += 256) {
        int uu = idx & 31, k8 = (idx >> 5) % 96, g = idx / (96 * 32);
        const float* src = whh + (long)(g * H_ + u0 + uu) * H_ + k8 * 8;
        f32x4 a = *(const f32x4*)src;
        f32x4 b2 = *(const f32x4*)(src + 4);
        f16x8 pk = {(f16)a.x, (f16)a.y, (f16)a.z, (f16)a.w,
                    (f16)b2.x, (f16)b2.y, (f16)b2.z, (f16)b2.w};
        wsvu[idx] = __builtin_bit_cast(ui4v, pk);
    }
    const bool own = (tid & 7) == 0;
    const int unit = tid >> 3;                // 0..31
    const int jl = tid & 7;
    float b_r = 0.f, b_z = 0.f, b_n = 0.f;
    if (own) {
        int c = u0 + unit;
        b_r = bhh[c];
        b_z = bhh[H_ + c];
        b_n = bhh[2 * H_ + c];
    }
    __syncthreads();
    const int u = tid & 31, q = tid >> 5, lane = tid & 63;
    const int pw = (tid >> 6) * 192 + lane;   // this wave's h-word base
    ui4v wreg[3][12];
#pragma unroll
    for (int g = 0; g < 3; ++g)
#pragma unroll
        for (int i = 0; i < 12; ++i)
            wreg[g][i] = wsvu[(g * 96 + q * 12 + i) * 32 + u];
    ull* base = hbuf + (long)chain * 1536;
    float g0 = 0.f, g1 = 0.f, g2v = 0.f;
    if (own) {
        const float* gp = gi + (long)chain * 270 * H3;
        int c = u0 + unit;
        g0 = gp[c];
        g1 = gp[H_ + c];
        g2v = gp[2 * H_ + c];
    }
    for (int s = 0; s < 270; ++s) {
        const ull* rb = base + (s & 1) * 768;
        ull* wb = base + ((s + 1) & 1) * 768;
        const unsigned want = (unsigned)s;
        ull v0, v1, v2, vh = 0;
        for (;;) {
            v0 = __hip_atomic_load(rb + pw, __ATOMIC_RELAXED, __HIP_MEMORY_SCOPE_AGENT);
            v1 = __hip_atomic_load(rb + pw + 64, __ATOMIC_RELAXED, __HIP_MEMORY_SCOPE_AGENT);
            v2 = __hip_atomic_load(rb + pw + 128, __ATOMIC_RELAXED, __HIP_MEMORY_SCOPE_AGENT);
            bool ok = ((unsigned)(v0 >> 32) == want) & ((unsigned)(v1 >> 32) == want) &
                      ((unsigned)(v2 >> 32) == want);
            if (own) {
                vh = __hip_atomic_load(rb + u0 + unit, __ATOMIC_RELAXED, __HIP_MEMORY_SCOPE_AGENT);
                ok &= ((unsigned)(vh >> 32) == want);
            }
            if (ok) break;
        }
        hsf[pw] = (f16)__uint_as_float((unsigned)v0);
        hsf[pw + 64] = (f16)__uint_as_float((unsigned)v1);
        hsf[pw + 128] = (f16)__uint_as_float((unsigned)v2);
        __builtin_amdgcn_wave_barrier();
        float ar = 0.f, az = 0.f, an = 0.f;
#pragma unroll
        for (int i = 0; i < 12; ++i) {
            ui4v hv = *(const ui4v*)(&hsf[(q * 12 + i) * 8]);
            ui4v wr = wreg[0][i], wz = wreg[1][i], wn = wreg[2][i];
            ar = fd2(hv.x, wr.x, ar); ar = fd2(hv.y, wr.y, ar);
            ar = fd2(hv.z, wr.z, ar); ar = fd2(hv.w, wr.w, ar);
            az = fd2(hv.x, wz.x, az); az = fd2(hv.y, wz.y, az);
            az = fd2(hv.z, wz.z, az); az = fd2(hv.w, wz.w, az);
            an = fd2(hv.x, wn.x, an); an = fd2(hv.y, wn.y, an);
            an = fd2(hv.z, wn.z, an); an = fd2(hv.w, wn.w, an);
        }
        const int par = s & 1;
        part[par][q][u][0] = ar;
        part[par][q][u][1] = az;
        part[par][q][u][2] = an;
        __syncthreads();                       // B: partials ready (block-wide)
        // parallel finisher: 8 lanes per unit butterfly-reduce, owner computes
        float gr = part[par][jl][unit][0];
        float gz = part[par][jl][unit][1];
        float gn = part[par][jl][unit][2];
        gr += __shfl_xor(gr, 1); gz += __shfl_xor(gz, 1); gn += __shfl_xor(gn, 1);
        gr += __shfl_xor(gr, 2); gz += __shfl_xor(gz, 2); gn += __shfl_xor(gn, 2);
        gr += __shfl_xor(gr, 4); gz += __shfl_xor(gz, 4); gn += __shfl_xor(gn, 4);
        if (own) {
            gr += b_r; gz += b_z; gn += b_n;
            float hold = __uint_as_float((unsigned)vh);
            float rg = 1.f / (1.f + __expf(-(g0 + gr)));
            float zg = 1.f / (1.f + __expf(-(g1 + gz)));
            float xa = g2v + rg * gn;
            float e2 = __expf(-2.f * xa);
            float ng = (1.f - e2) / (1.f + e2);
            float hnew = (1.f - zg) * ng + zg * hold;
            int c = u0 + unit;
            ull wvv = ((ull)(unsigned)(s + 1) << 32) | (ull)__float_as_uint(hnew);
            __hip_atomic_store(wb + c, wvv, __ATOMIC_RELAXED, __HIP_MEMORY_SCOPE_AGENT);
            long row = (long)chain * 270 + s;
            f16 h16 = (f16)hnew;
            Hhi[row * H_ + c] = h16;
            Hlo[row * H_ + c] = (f16)(hnew - (float)h16);
            if (s < 269) {   // prefetch next step's gi (hidden behind next poll)
                const float* gp = gi + ((long)chain * 270 + s + 1) * H3;
                g0 = gp[c];
                g1 = gp[H_ + c];
                g2v = gp[2 * H_ + c];
            }
        }
    }
}

// ---------------------------------------------------------------- attention softmax
__global__ __launch_bounds__(256) void k_attn_softmax(const float* __restrict__ lg,
                                                      const int* __restrict__ x, f16* __restrict__ ah) {
    __shared__ float red[256];
    int r = blockIdx.x, tid = threadIdx.x;
    int b = r / 270;
    const float* lr = lg + (long)r * S_;
    const int* xb = x + (long)b * S_;
    float v0 = lr[tid];
    if (xb[tid] == 0) v0 = -1e9f;
    float v1 = lr[tid + 256];
    if (xb[tid + 256] == 0) v1 = -1e9f;
    red[tid] = fmaxf(v0, v1);
    __syncthreads();
    for (int o = 128; o > 0; o >>= 1) {
        if (tid < o) red[tid] = fmaxf(red[tid], red[tid + o]);
        __syncthreads();
    }
    float m = red[0];
    __syncthreads();
    float e0 = __expf(v0 - m), e1 = __expf(v1 - m);
    red[tid] = e0 + e1;
    __syncthreads();
    for (int o = 128; o > 0; o >>= 1) {
        if (tid < o) red[tid] += red[tid + o];
        __syncthreads();
    }
    float inv = 1.f / red[0];
    ah[(long)r * S_ + tid] = (f16)(e0 * inv);
    ah[(long)r * S_ + tid + 256] = (f16)(e1 * inv);
}

// ---------------------------------------------------------------- p_gen
__global__ __launch_bounds__(256) void k_pgen(const f16* __restrict__ Wall, const f16* __restrict__ Hhi,
                                              const f16* __restrict__ Hlo, const float* __restrict__ ctx,
                                              const float* __restrict__ wg, const float* __restrict__ wgb,
                                              float* __restrict__ pg) {
    __shared__ float red[256];
    int r = blockIdx.x, tid = threadIdx.x;
    float a = 0.f;
    for (int i = tid; i < H_; i += 256) {
        a += (float)Wall[(long)r * H_ + i] * wg[i];
        a += ((float)Hhi[(long)r * H_ + i] + (float)Hlo[(long)r * H_ + i]) * wg[H_ + i];
        a += ctx[(long)r * H_ + i] * wg[2 * H_ + i];
    }
    red[tid] = a;
    __syncthreads();
    for (int o = 128; o > 0; o >>= 1) {
        if (tid < o) red[tid] += red[tid + o];
        __syncthreads();
    }
    if (tid == 0) pg[r] = 1.f / (1.f + expf(-(red[0] + wgb[0])));
}

// ---------------------------------------------------------------- fused rinv + finalize + scatter
__global__ __launch_bounds__(256, 1) void k_fin3(float* __restrict__ out,
                                                 const float* __restrict__ psum,
                                                 const float* __restrict__ pg,
                                                 const f16* __restrict__ ah,
                                                 const int* __restrict__ x) {
    __shared__ float row[V_];
    __shared__ float red[256];
    const int r = blockIdx.x, tid = threadIdx.x;
    const int b = r / 270;
    float s = 0.f;
    for (int i = tid; i < VNT; i += 256) s += psum[(long)i * R_ + r];
    red[tid] = s;
    __syncthreads();
    for (int o = 128; o > 0; o >>= 1) {
        if (tid < o) red[tid] += red[tid + o];
        __syncthreads();
    }
    const float pgv = pg[r];
    const float scale = pgv / red[0];
    float* orow = out + (long)r * V_;
    for (int i = tid; i < V_ / 4; i += 256) {
        f32x4 v = ((const f32x4*)orow)[i];
        v.x *= scale;
        v.y *= scale;
        v.z *= scale;
        v.w *= scale;
        ((f32x4*)row)[i] = v;
    }
    __syncthreads();
    const float om = 1.f - pgv;
    for (int s2 = tid; s2 < S_; s2 += 256) {
        int xv = x[(long)b * S_ + s2];
        if (xv != 0) {
            float a = (float)ah[(long)r * S_ + s2];
            if (a != 0.f) atomicAdd(&row[xv], om * a);
        }
    }
    __syncthreads();
    for (int i = tid; i < V_ / 4; i += 256)
        ((f32x4*)orow)[i] = ((const f32x4*)row)[i];
}

// ---------------------------------------------------------------- host
extern "C" void kernel_launch(void* const* d_in, const int* in_sizes, int n_in, void* d_out,
                              int out_size, void* d_ws, size_t ws_size, hipStream_t stream) {
    (void)in_sizes; (void)n_in; (void)out_size; (void)ws_size;
    const int* x = (const int*)d_in[0];
    const float* dec = (const float*)d_in[1];
    const float* enc = (const float*)d_in[2];
    const float* hid = (const float*)d_in[3];
    const int* tea = (const int*)d_in[4];
    const float* emb = (const float*)d_in[6];
    const float* wih = (const float*)d_in[7];
    const float* whh = (const float*)d_in[8];
    const float* bih = (const float*)d_in[9];
    const float* bhh = (const float*)d_in[10];
    const float* wgw = (const float*)d_in[11];
    const float* wgb = (const float*)d_in[12];
    float* out = (float*)d_out;

    char* w = (char*)d_ws;
    size_t off = 0;
    auto alloc = [&](size_t bytes) {
        void* p = w + off;
        off = (off + bytes + 255) & ~(size_t)255;
        return p;
    };
    ull* hbuf = (ull*)alloc(8 * 1536 * 8);          // [chain][parity][768] seq-tagged h
    f16* Wall = (f16*)alloc((size_t)R_ * H_ * 2);
    f16* wih16 = (f16*)alloc((size_t)H3 * H_ * 2);
    float* giA = (float*)alloc((size_t)R_ * H3 * 4);
    f16* Hhi = (f16*)alloc((size_t)R_ * H_ * 2);
    f16* Hlo = (f16*)alloc((size_t)R_ * H_ * 2);
    f16* emb16 = (f16*)alloc((size_t)V_ * H_ * 2);
    f16* ehi = (f16*)alloc((size_t)B_ * S_ * H_ * 2);
    f16* elo = (f16*)alloc((size_t)B_ * S_ * H_ * 2);
    f16* encT = (f16*)alloc((size_t)B_ * H_ * S_ * 2);
    float* lgH = (float*)alloc((size_t)R_ * S_ * 4);
    f16* ah = (f16*)alloc((size_t)R_ * S_ * 2);
    float* ctx = (float*)alloc((size_t)R_ * H_ * 4);
    float* pg = (float*)alloc(R_ * 4);
    float* psum = (float*)alloc((size_t)VNT * R_ * 4);

    k_init_h<<<24, 256, 0, stream>>>(hid, hbuf);
    k_prep<<<R_ + CASTB, 256, 0, stream>>>(emb, dec, tea, Wall, wih, wih16);

    // gi = W_all @ w_ih^T + b_ih
    {
        dim3 g(H3 / 128, (R_ + 127) / 128, 1);
        k_gemm<1><<<g, 256, 0, stream>>>(Wall, wih16, giA, bih, R_, H3, H_, 0, 0, 0);
    }
    // recurrence (blocks 0-191) + hidden preps on idle CUs (blocks 192-255)
    k_gru<<<256, 256, 0, stream>>>(giA, whh, bhh, hbuf, Hhi, Hlo,
                                   emb, emb16, enc, ehi, elo, encT);

    // attention logits (merged hi/lo): Hhi*Ehi + Hhi*Elo + Hlo*Ehi
    {
        dim3 g(S_ / 128, 3, 8);
        k_attn3<<<g, 256, 0, stream>>>(Hhi, Hlo, ehi, elo, lgH, 270, S_, H_,
                                       270L * H_, (long)S_ * H_, 270L * S_);
    }
    k_attn_softmax<<<R_, 256, 0, stream>>>(lgH, x, ah);
    {
        dim3 g(H_ / 128, 3, 8);
        k_gemm<0><<<g, 256, 0, stream>>>(ah, encT, ctx, nullptr, 270, H_, S_, 270L * S_, (long)H_ * S_, 270L * H_);
    }
    k_pgen<<<R_, 256, 0, stream>>>(Wall, Hhi, Hlo, ctx, wgw, wgb, pg);

    // vocab: out = exp(Hhi @ emb16^T), row partial sums -> psum (XCD-swizzled grid)
    k_vocab<<<VMT * VNT, 256, 0, stream>>>(Hhi, emb16, out, psum);
    // fused rinv + finalize + pointer-scatter
    k_fin3<<<R_, 256, 0, stream>>>(out, psum, pg, ah, x);
}

// Round 15
// 1116.845 us; speedup vs baseline: 1.0962x; 1.0187x over previous
//
#include <hip/hip_runtime.h>
#include <hip/hip_bf16.h>

typedef _Float16 f16;
typedef _Float16 f16x8 __attribute__((ext_vector_type(8)));
typedef _Float16 f16x4v __attribute__((ext_vector_type(4)));
typedef _Float16 h2 __attribute__((ext_vector_type(2)));
typedef float f32x4 __attribute__((ext_vector_type(4)));
typedef unsigned ui4v __attribute__((ext_vector_type(4)));
typedef unsigned long long ull;

#define B_ 8
#define S_ 512
#define H_ 768
#define V_ 35004
#define J_ 30
#define K_ 9
#define R_ 2160          // out rows, r = b*270 + j*9 + t
#define H3 2304
#define VMT 17           // vocab M tiles
#define VNT 274          // vocab N tiles
#define CASTB 864        // extra blocks in k_prep for wih cast

// ---------------------------------------------------------------- prep kernels

// rows < R_: build W_all; rows >= R_: cast wih -> f16
__global__ void k_prep(const float* __restrict__ emb, const float* __restrict__ dec,
                       const int* __restrict__ teacher, f16* __restrict__ Wall,
                       const float* __restrict__ wih, f16* __restrict__ wih16) {
    int r = blockIdx.x;
    if (r < R_) {
        int b = r / 270, s = r % 270, j = s / 9, t = s % 9;
        const float* src = (t == 0) ? dec + ((long)b * J_ + j) * H_
                                    : emb + (long)teacher[((long)b * J_ + j) * K_ + (t - 1)] * H_;
        f16* dst = Wall + (long)r * H_;
        for (int c = threadIdx.x; c < H_; c += 256) dst[c] = (f16)src[c];
    } else {
        const long n = (long)H3 * H_;
        for (long i = (long)(r - R_) * 256 + threadIdx.x; i < n; i += (long)CASTB * 256)
            wih16[i] = (f16)wih[i];
    }
}

// h exchange word: {seq:32 | f32 bits:32}; chain-major [chain][parity][768].
// Writes BOTH parities every call (replay-deterministic).
__global__ void k_init_h(const float* __restrict__ hidden, ull* __restrict__ hbuf) {
    int i = blockIdx.x * 256 + threadIdx.x;
    if (i < B_ * H_) {
        int b = i / H_, u = i % H_;
        hbuf[(long)b * 1536 + u] = (ull)__float_as_uint(hidden[i]);  // seq 0, parity 0
        hbuf[(long)b * 1536 + 768 + u] = 0;                          // parity 1 cleared
    }
}

// ---------------------------------------------------------------- shared GEMM helpers
typedef const __attribute__((address_space(1))) unsigned GASU;
typedef __attribute__((address_space(3))) unsigned LASU;
__device__ __forceinline__ void gld16(const f16* g, f16* l) {
    __builtin_amdgcn_global_load_lds((GASU*)g, (LASU*)l, 16, 0, 0);
}

// ---------------------------------------------------------------- f16 MFMA GEMM (m97 structure)
// C[M,N] = A[M,K] @ B[N,K]^T ; MODE 0: store, 1: store + bias[col]
template <int MODE>
__global__ __launch_bounds__(256) void k_gemm(const f16* __restrict__ A, const f16* __restrict__ Bm,
                                              float* __restrict__ C, const float* __restrict__ bias,
                                              int M, int N, int K, long sA, long sB, long sC) {
    A += (long)blockIdx.z * sA;
    Bm += (long)blockIdx.z * sB;
    C += (long)blockIdx.z * sC;
    const int m0 = blockIdx.y * 128, n0 = blockIdx.x * 128;
    __shared__ f16 As[128 * 32];
    __shared__ f16 Bs[128 * 32];
    const int tid = threadIdx.x, lane = tid & 63, wave = tid >> 6;
    const int wm = wave >> 1, wn = wave & 1;
    const int fr = lane & 15, kg = lane >> 4;
    f32x4 acc[4][4] = {};
    const int idxu = wave * 128;
    const int i0 = idxu + lane, i1 = idxu + 64 + lane;
    const int r0 = i0 >> 2, k80 = i0 & 3;
    const int r1 = i1 >> 2, k81 = i1 & 3;
    int ga0 = m0 + r0; if (ga0 >= M) ga0 = M - 1;
    int ga1 = m0 + r1; if (ga1 >= M) ga1 = M - 1;
    int gb0 = n0 + r0; if (gb0 >= N) gb0 = N - 1;
    int gb1 = n0 + r1; if (gb1 >= N) gb1 = N - 1;
    const f16* pa0 = A + (long)ga0 * K + k80 * 8;
    const f16* pa1 = A + (long)ga1 * K + k81 * 8;
    const f16* pb0 = Bm + (long)gb0 * K + k80 * 8;
    const f16* pb1 = Bm + (long)gb1 * K + k81 * 8;
    for (int kt = 0; kt < K; kt += 32) {
        gld16(pa0 + kt, As + idxu * 8);
        gld16(pa1 + kt, As + idxu * 8 + 512);
        gld16(pb0 + kt, Bs + idxu * 8);
        gld16(pb1 + kt, Bs + idxu * 8 + 512);
        __syncthreads();
        f16x8 af[4], bf[4];
#pragma unroll
        for (int m = 0; m < 4; ++m) af[m] = *(const f16x8*)(As + (wm * 64 + m * 16 + fr) * 32 + kg * 8);
#pragma unroll
        for (int n = 0; n < 4; ++n) bf[n] = *(const f16x8*)(Bs + (wn * 64 + n * 16 + fr) * 32 + kg * 8);
#pragma unroll
        for (int m = 0; m < 4; ++m)
#pragma unroll
            for (int n = 0; n < 4; ++n)
                acc[m][n] = __builtin_amdgcn_mfma_f32_16x16x32_f16(af[m], bf[n], acc[m][n], 0, 0, 0);
        __syncthreads();
    }
    const int crow = m0 + wm * 64 + (lane >> 4) * 4;
    const int ccol = n0 + wn * 64 + fr;
#pragma unroll
    for (int n = 0; n < 4; ++n) {
        int col = ccol + n * 16;
        if (col >= N) continue;
        float bv = (MODE == 1) ? bias[col] : 0.f;
#pragma unroll
        for (int m = 0; m < 4; ++m) {
#pragma unroll
            for (int q = 0; q < 4; ++q) {
                int row = crow + m * 16 + q;
                if (row < M) C[(long)row * N + col] = acc[m][n][q] + bv;
            }
        }
    }
}

// ---------------------------------------------------------------- merged hi/lo attention logits
__global__ __launch_bounds__(256) void k_attn3(const f16* __restrict__ Ahi, const f16* __restrict__ Alo,
                                               const f16* __restrict__ Bhi, const f16* __restrict__ Blo,
                                               float* __restrict__ C, int M, int N, int K,
                                               long sA, long sB, long sC) {
    const long za = (long)blockIdx.z * sA, zb = (long)blockIdx.z * sB;
    C += (long)blockIdx.z * sC;
    const int m0 = blockIdx.y * 128, n0 = blockIdx.x * 128;
    __shared__ f16 As[128 * 32];
    __shared__ f16 Bs[128 * 32];
    const int tid = threadIdx.x, lane = tid & 63, wave = tid >> 6;
    const int wm = wave >> 1, wn = wave & 1;
    const int fr = lane & 15, kg = lane >> 4;
    f32x4 acc[4][4] = {};
    const int idxu = wave * 128;
    const int i0 = idxu + lane, i1 = idxu + 64 + lane;
    const int r0 = i0 >> 2, k80 = i0 & 3;
    const int r1 = i1 >> 2, k81 = i1 & 3;
    int ga0 = m0 + r0; if (ga0 >= M) ga0 = M - 1;
    int ga1 = m0 + r1; if (ga1 >= M) ga1 = M - 1;
    int gb0 = n0 + r0; if (gb0 >= N) gb0 = N - 1;
    int gb1 = n0 + r1; if (gb1 >= N) gb1 = N - 1;
    const long oa0 = (long)ga0 * K + k80 * 8, oa1 = (long)ga1 * K + k81 * 8;
    const long ob0 = (long)gb0 * K + k80 * 8, ob1 = (long)gb1 * K + k81 * 8;
    for (int ph = 0; ph < 3; ++ph) {
        const f16* Ap = (ph == 2 ? Alo : Ahi) + za;
        const f16* Bp = (ph == 1 ? Blo : Bhi) + zb;
        for (int kt = 0; kt < K; kt += 32) {
            gld16(Ap + oa0 + kt, As + idxu * 8);
            gld16(Ap + oa1 + kt, As + idxu * 8 + 512);
            gld16(Bp + ob0 + kt, Bs + idxu * 8);
            gld16(Bp + ob1 + kt, Bs + idxu * 8 + 512);
            __syncthreads();
            f16x8 af[4], bf[4];
#pragma unroll
            for (int m = 0; m < 4; ++m) af[m] = *(const f16x8*)(As + (wm * 64 + m * 16 + fr) * 32 + kg * 8);
#pragma unroll
            for (int n = 0; n < 4; ++n) bf[n] = *(const f16x8*)(Bs + (wn * 64 + n * 16 + fr) * 32 + kg * 8);
#pragma unroll
            for (int m = 0; m < 4; ++m)
#pragma unroll
                for (int n = 0; n < 4; ++n)
                    acc[m][n] = __builtin_amdgcn_mfma_f32_16x16x32_f16(af[m], bf[n], acc[m][n], 0, 0, 0);
            __syncthreads();
        }
    }
    const int crow = m0 + wm * 64 + (lane >> 4) * 4;
    const int ccol = n0 + wn * 64 + fr;
#pragma unroll
    for (int n = 0; n < 4; ++n) {
        int col = ccol + n * 16;
        if (col >= N) continue;
#pragma unroll
        for (int m = 0; m < 4; ++m) {
#pragma unroll
            for (int q = 0; q < 4; ++q) {
                int row = crow + m * 16 + q;
                if (row < M) C[(long)row * N + col] = acc[m][n][q];
            }
        }
    }
}

// ---------------------------------------------------------------- vocab GEMM: out=exp(Hhi@emb^T)+psum
__global__ __launch_bounds__(256) void k_vocab(const f16* __restrict__ A, const f16* __restrict__ Bm,
                                               float* __restrict__ C, float* __restrict__ psum) {
    const int M = R_, N = V_, K = H_;
    const int nwg = VMT * VNT;
    int lin = blockIdx.x;
    int q8 = nwg / 8, r8 = nwg % 8;
    int xcd = lin & 7, idx = lin >> 3;
    int newlin = (xcd < r8) ? xcd * (q8 + 1) + idx : r8 * (q8 + 1) + (xcd - r8) * q8 + idx;
    int mt = newlin % VMT, nt = newlin / VMT;
    const int m0 = mt * 128, n0 = nt * 128;
    __shared__ f16 As[128 * 32];
    __shared__ f16 Bs[128 * 32];
    __shared__ float rpart[2][128];
    const int tid = threadIdx.x, lane = tid & 63, wave = tid >> 6;
    const int wm = wave >> 1, wn = wave & 1;
    const int fr = lane & 15, kg = lane >> 4;
    f32x4 acc[4][4] = {};
    const int idxu = wave * 128;
    const int i0 = idxu + lane, i1 = idxu + 64 + lane;
    const int r0 = i0 >> 2, k80 = i0 & 3;
    const int r1 = i1 >> 2, k81 = i1 & 3;
    int ga0 = m0 + r0; if (ga0 >= M) ga0 = M - 1;
    int ga1 = m0 + r1; if (ga1 >= M) ga1 = M - 1;
    int gb0 = n0 + r0; if (gb0 >= N) gb0 = N - 1;
    int gb1 = n0 + r1; if (gb1 >= N) gb1 = N - 1;
    const f16* pa0 = A + (long)ga0 * K + k80 * 8;
    const f16* pa1 = A + (long)ga1 * K + k81 * 8;
    const f16* pb0 = Bm + (long)gb0 * K + k80 * 8;
    const f16* pb1 = Bm + (long)gb1 * K + k81 * 8;
    for (int kt = 0; kt < K; kt += 32) {
        gld16(pa0 + kt, As + idxu * 8);
        gld16(pa1 + kt, As + idxu * 8 + 512);
        gld16(pb0 + kt, Bs + idxu * 8);
        gld16(pb1 + kt, Bs + idxu * 8 + 512);
        __syncthreads();
        f16x8 af[4], bf[4];
#pragma unroll
        for (int m = 0; m < 4; ++m) af[m] = *(const f16x8*)(As + (wm * 64 + m * 16 + fr) * 32 + kg * 8);
#pragma unroll
        for (int n = 0; n < 4; ++n) bf[n] = *(const f16x8*)(Bs + (wn * 64 + n * 16 + fr) * 32 + kg * 8);
#pragma unroll
        for (int m = 0; m < 4; ++m)
#pragma unroll
            for (int n = 0; n < 4; ++n)
                acc[m][n] = __builtin_amdgcn_mfma_f32_16x16x32_f16(af[m], bf[n], acc[m][n], 0, 0, 0);
        __syncthreads();
    }
    const int crow = m0 + wm * 64 + (lane >> 4) * 4;
    const int ccol = n0 + wn * 64 + fr;
    float rs[4][4];
#pragma unroll
    for (int m = 0; m < 4; ++m)
#pragma unroll
        for (int q = 0; q < 4; ++q) rs[m][q] = 0.f;
#pragma unroll
    for (int n = 0; n < 4; ++n) {
        int col = ccol + n * 16;
        if (col >= N) continue;
#pragma unroll
        for (int m = 0; m < 4; ++m) {
#pragma unroll
            for (int q = 0; q < 4; ++q) {
                int row = crow + m * 16 + q;
                if (row < M) {
                    float e = __expf(acc[m][n][q]);
                    C[(long)row * N + col] = e;
                    rs[m][q] += e;
                }
            }
        }
    }
#pragma unroll
    for (int m = 0; m < 4; ++m)
#pragma unroll
        for (int q = 0; q < 4; ++q) {
            float v = rs[m][q];
            v += __shfl_xor(v, 1);
            v += __shfl_xor(v, 2);
            v += __shfl_xor(v, 4);
            v += __shfl_xor(v, 8);
            rs[m][q] = v;
        }
    if ((lane & 15) == 0) {
#pragma unroll
        for (int m = 0; m < 4; ++m)
#pragma unroll
            for (int q = 0; q < 4; ++q)
                rpart[wn][wm * 64 + (lane >> 4) * 4 + m * 16 + q] = rs[m][q];
    }
    __syncthreads();
    if (tid < 128) {
        int row = m0 + tid;
        if (row < M) psum[(long)nt * M + row] = rpart[0][tid] + rpart[1][tid];
    }
}

// ---------------------------------------------------------------- GRU recurrence + hidden preps
__device__ __forceinline__ float fd2(unsigned hv, unsigned wv, float acc) {
#if __has_builtin(__builtin_amdgcn_fdot2)
    return __builtin_amdgcn_fdot2(__builtin_bit_cast(h2, hv), __builtin_bit_cast(h2, wv), acc, false);
#else
    h2 a = __builtin_bit_cast(h2, hv), b = __builtin_bit_cast(h2, wv);
    return acc + (float)a.x * (float)b.x + (float)a.y * (float)b.y;
#endif
}

__global__ __launch_bounds__(256, 1) void k_gru(const float* __restrict__ gi,
                                                const float* __restrict__ whh,
                                                const float* __restrict__ bhh,
                                                ull* hbuf,
                                                f16* __restrict__ Hhi, f16* __restrict__ Hlo,
                                                const float* __restrict__ emb, f16* __restrict__ emb16,
                                                const float* __restrict__ enc, f16* __restrict__ ehi,
                                                f16* __restrict__ elo, f16* __restrict__ encT) {
    __shared__ ui4v wsvu[9216];               // weights (recurrence) / transpose tile (prep)
    __shared__ __align__(16) f16 hsf[768];
    __shared__ float part[2][8][32][3];       // [parity][octant][unit][gate] (R12-proven, 0 conflicts)
    const int tid = threadIdx.x;
    if (blockIdx.x >= 192) {
        // ---------- hidden prep on idle CUs ----------
        const long pt = (long)(blockIdx.x - 192) * 256 + tid;
        const long n4 = (long)V_ * H_ / 4;
        for (long i = pt; i < n4; i += 64 * 256) {
            f32x4 v = ((const f32x4*)emb)[i];
            f16x4v r = {(f16)v.x, (f16)v.y, (f16)v.z, (f16)v.w};
            ((f16x4v*)emb16)[i] = r;
        }
        const long n4e = (long)B_ * S_ * H_ / 4;
        for (long i = pt; i < n4e; i += 64 * 256) {
            f32x4 v = ((const f32x4*)enc)[i];
            f16 h0 = (f16)v.x, h1 = (f16)v.y, h2v = (f16)v.z, h3 = (f16)v.w;
            f16x4v hv = {h0, h1, h2v, h3};
            ((f16x4v*)ehi)[i] = hv;
            f16x4v lv = {(f16)(v.x - (float)h0), (f16)(v.y - (float)h1),
                         (f16)(v.z - (float)h2v), (f16)(v.w - (float)h3)};
            ((f16x4v*)elo)[i] = lv;
        }
        // encT via LDS-tiled transpose (64x64 f32 tile, pad 65)
        float* tl = (float*)wsvu;
        for (int t = blockIdx.x - 192; t < 8 * 8 * 12; t += 64) {
            int ht = t % 12, st = (t / 12) % 8, bb = t / 96;
            __syncthreads();
#pragma unroll
            for (int k = 0; k < 16; ++k) {
                int i = tid + k * 256;
                int sl = i >> 6, hl = i & 63;
                tl[sl * 65 + hl] = enc[((long)bb * S_ + st * 64 + sl) * H_ + ht * 64 + hl];
            }
            __syncthreads();
#pragma unroll
            for (int k = 0; k < 16; ++k) {
                int i = tid + k * 256;
                int hl = i >> 6, sl = i & 63;
                encT[((long)bb * H_ + ht * 64 + hl) * S_ + st * 64 + sl] = (f16)tl[sl * 65 + hl];
            }
        }
        return;
    }
    // ---------- recurrence ----------
    const int chain = blockIdx.x / 24;
    const int blk = blockIdx.x % 24;
    const int u0 = blk * 32;
    for (int idx = tid; idx < 9216; idx += 256) {
        int uu = idx & 31, k8 = (idx >> 5) % 96, g = idx / (96 * 32);
        const float* src = whh + (long)(g * H_ + u0 + uu) * H_ + k8 * 8;
        f32x4 a = *(const f32x4*)src;
        f32x4 b2 = *(const f32x4*)(src + 4);
        f16x8 pk = {(f16)a.x, (f16)a.y, (f16)a.z, (f16)a.w,
                    (f16)b2.x, (f16)b2.y, (f16)b2.z, (f16)b2.w};
        wsvu[idx] = __builtin_bit_cast(ui4v, pk);
    }
    float b_r = 0.f, b_z = 0.f, b_n = 0.f;
    if (tid < 32) {
        int c = u0 + tid;
        b_r = bhh[c];
        b_z = bhh[H_ + c];
        b_n = bhh[2 * H_ + c];
    }
    __syncthreads();
    const int u = tid & 31, q = tid >> 5, lane = tid & 63;
    const int pw = (tid >> 6) * 192 + lane;   // this wave's h-word base
    ui4v wreg[3][12];
#pragma unroll
    for (int g = 0; g < 3; ++g)
#pragma unroll
        for (int i = 0; i < 12; ++i)
            wreg[g][i] = wsvu[(g * 96 + q * 12 + i) * 32 + u];
    ull* base = hbuf + (long)chain * 1536;
    const bool fin = (tid < 32);
    float g0 = 0.f, g1 = 0.f, g2v = 0.f;
    if (fin) {
        const float* gp = gi + (long)chain * 270 * H3;
        int c = u0 + tid;
        g0 = gp[c];
        g1 = gp[H_ + c];
        g2v = gp[2 * H_ + c];
    }
    for (int s = 0; s < 270; ++s) {
        const ull* rb = base + (s & 1) * 768;
        ull* wb = base + ((s + 1) & 1) * 768;
        const unsigned want = (unsigned)s;
        ull v0, v1, v2, vh = 0;
        for (;;) {
            v0 = __hip_atomic_load(rb + pw, __ATOMIC_RELAXED, __HIP_MEMORY_SCOPE_AGENT);
            v1 = __hip_atomic_load(rb + pw + 64, __ATOMIC_RELAXED, __HIP_MEMORY_SCOPE_AGENT);
            v2 = __hip_atomic_load(rb + pw + 128, __ATOMIC_RELAXED, __HIP_MEMORY_SCOPE_AGENT);
            bool ok = ((unsigned)(v0 >> 32) == want) & ((unsigned)(v1 >> 32) == want) &
                      ((unsigned)(v2 >> 32) == want);
            if (fin) {
                vh = __hip_atomic_load(rb + u0 + tid, __ATOMIC_RELAXED, __HIP_MEMORY_SCOPE_AGENT);
                ok &= ((unsigned)(vh >> 32) == want);
            }
            if (ok) break;
        }
        hsf[pw] = (f16)__uint_as_float((unsigned)v0);
        hsf[pw + 64] = (f16)__uint_as_float((unsigned)v1);
        hsf[pw + 128] = (f16)__uint_as_float((unsigned)v2);
        __builtin_amdgcn_wave_barrier();
        float ar = 0.f, az = 0.f, an = 0.f;
#pragma unroll
        for (int i = 0; i < 12; ++i) {
            ui4v hv = *(const ui4v*)(&hsf[(q * 12 + i) * 8]);
            ui4v wr = wreg[0][i], wz = wreg[1][i], wn = wreg[2][i];
            ar = fd2(hv.x, wr.x, ar); ar = fd2(hv.y, wr.y, ar);
            ar = fd2(hv.z, wr.z, ar); ar = fd2(hv.w, wr.w, ar);
            az = fd2(hv.x, wz.x, az); az = fd2(hv.y, wz.y, az);
            az = fd2(hv.z, wz.z, az); az = fd2(hv.w, wz.w, az);
            an = fd2(hv.x, wn.x, an); an = fd2(hv.y, wn.y, an);
            an = fd2(hv.z, wn.z, an); an = fd2(hv.w, wn.w, an);
        }
        const int par = s & 1;
        part[par][q][u][0] = ar;
        part[par][q][u][1] = az;
        part[par][q][u][2] = an;
        __syncthreads();                       // B: partials ready (block-wide)
        if (fin) {
            float gr = b_r, gz = b_z, gn = b_n;
#pragma unroll
            for (int qq = 0; qq < 8; ++qq) {
                gr += part[par][qq][tid][0];
                gz += part[par][qq][tid][1];
                gn += part[par][qq][tid][2];
            }
            float hold = __uint_as_float((unsigned)vh);
            float rg = 1.f / (1.f + __expf(-(g0 + gr)));
            float zg = 1.f / (1.f + __expf(-(g1 + gz)));
            float xa = g2v + rg * gn;
            float e2 = __expf(-2.f * xa);
            float ng = (1.f - e2) / (1.f + e2);
            float hnew = (1.f - zg) * ng + zg * hold;
            int c = u0 + tid;
            ull wvv = ((ull)(unsigned)(s + 1) << 32) | (ull)__float_as_uint(hnew);
            __hip_atomic_store(wb + c, wvv, __ATOMIC_RELAXED, __HIP_MEMORY_SCOPE_AGENT);
            long row = (long)chain * 270 + s;
            f16 h16 = (f16)hnew;
            Hhi[row * H_ + c] = h16;
            Hlo[row * H_ + c] = (f16)(hnew - (float)h16);
            if (s < 269) {   // prefetch next step's gi (hidden behind next poll)
                const float* gp = gi + ((long)chain * 270 + s + 1) * H3;
                g0 = gp[c];
                g1 = gp[H_ + c];
                g2v = gp[2 * H_ + c];
            }
        }
    }
}

// ---------------------------------------------------------------- attention softmax
__global__ __launch_bounds__(256) void k_attn_softmax(const float* __restrict__ lg,
                                                      const int* __restrict__ x, f16* __restrict__ ah) {
    __shared__ float red[256];
    int r = blockIdx.x, tid = threadIdx.x;
    int b = r / 270;
    const float* lr = lg + (long)r * S_;
    const int* xb = x + (long)b * S_;
    float v0 = lr[tid];
    if (xb[tid] == 0) v0 = -1e9f;
    float v1 = lr[tid + 256];
    if (xb[tid + 256] == 0) v1 = -1e9f;
    red[tid] = fmaxf(v0, v1);
    __syncthreads();
    for (int o = 128; o > 0; o >>= 1) {
        if (tid < o) red[tid] = fmaxf(red[tid], red[tid + o]);
        __syncthreads();
    }
    float m = red[0];
    __syncthreads();
    float e0 = __expf(v0 - m), e1 = __expf(v1 - m);
    red[tid] = e0 + e1;
    __syncthreads();
    for (int o = 128; o > 0; o >>= 1) {
        if (tid < o) red[tid] += red[tid + o];
        __syncthreads();
    }
    float inv = 1.f / red[0];
    ah[(long)r * S_ + tid] = (f16)(e0 * inv);
    ah[(long)r * S_ + tid + 256] = (f16)(e1 * inv);
}

// ---------------------------------------------------------------- fused p_gen + rinv + finalize + scatter
// One block per row: pg from Wall/H/ctx dot; rinv from psum; stream exp-row
// through LDS scaling by pg*rinv; pointer-scatter via LDS atomics; one writeback.
__global__ __launch_bounds__(256, 1) void k_fin3(float* __restrict__ out,
                                                 const float* __restrict__ psum,
                                                 const f16* __restrict__ Wall,
                                                 const f16* __restrict__ Hhi,
                                                 const f16* __restrict__ Hlo,
                                                 const float* __restrict__ ctx,
                                                 const float* __restrict__ wg,
                                                 const float* __restrict__ wgb,
                                                 const f16* __restrict__ ah,
                                                 const int* __restrict__ x) {
    __shared__ float row[V_];
    __shared__ float red[256], red2[256];
    const int r = blockIdx.x, tid = threadIdx.x;
    const int b = r / 270;
    // pg partial
    float a = 0.f;
    for (int i = tid; i < H_; i += 256) {
        a += (float)Wall[(long)r * H_ + i] * wg[i];
        a += ((float)Hhi[(long)r * H_ + i] + (float)Hlo[(long)r * H_ + i]) * wg[H_ + i];
        a += ctx[(long)r * H_ + i] * wg[2 * H_ + i];
    }
    // psum partial
    float s = 0.f;
    for (int i = tid; i < VNT; i += 256) s += psum[(long)i * R_ + r];
    red[tid] = s;
    red2[tid] = a;
    __syncthreads();
    for (int o = 128; o > 0; o >>= 1) {
        if (tid < o) {
            red[tid] += red[tid + o];
            red2[tid] += red2[tid + o];
        }
        __syncthreads();
    }
    const float pgv = 1.f / (1.f + __expf(-(red2[0] + wgb[0])));
    const float scale = pgv / red[0];
    float* orow = out + (long)r * V_;
    for (int i = tid; i < V_ / 4; i += 256) {
        f32x4 v = ((const f32x4*)orow)[i];
        v.x *= scale;
        v.y *= scale;
        v.z *= scale;
        v.w *= scale;
        ((f32x4*)row)[i] = v;
    }
    __syncthreads();
    const float om = 1.f - pgv;
    for (int s2 = tid; s2 < S_; s2 += 256) {
        int xv = x[(long)b * S_ + s2];
        if (xv != 0) {
            float av = (float)ah[(long)r * S_ + s2];
            if (av != 0.f) atomicAdd(&row[xv], om * av);
        }
    }
    __syncthreads();
    for (int i = tid; i < V_ / 4; i += 256)
        ((f32x4*)orow)[i] = ((const f32x4*)row)[i];
}

// ---------------------------------------------------------------- host
extern "C" void kernel_launch(void* const* d_in, const int* in_sizes, int n_in, void* d_out,
                              int out_size, void* d_ws, size_t ws_size, hipStream_t stream) {
    (void)in_sizes; (void)n_in; (void)out_size; (void)ws_size;
    const int* x = (const int*)d_in[0];
    const float* dec = (const float*)d_in[1];
    const float* enc = (const float*)d_in[2];
    const float* hid = (const float*)d_in[3];
    const int* tea = (const int*)d_in[4];
    const float* emb = (const float*)d_in[6];
    const float* wih = (const float*)d_in[7];
    const float* whh = (const float*)d_in[8];
    const float* bih = (const float*)d_in[9];
    const float* bhh = (const float*)d_in[10];
    const float* wgw = (const float*)d_in[11];
    const float* wgb = (const float*)d_in[12];
    float* out = (float*)d_out;

    char* w = (char*)d_ws;
    size_t off = 0;
    auto alloc = [&](size_t bytes) {
        void* p = w + off;
        off = (off + bytes + 255) & ~(size_t)255;
        return p;
    };
    ull* hbuf = (ull*)alloc(8 * 1536 * 8);          // [chain][parity][768] seq-tagged h
    f16* Wall = (f16*)alloc((size_t)R_ * H_ * 2);
    f16* wih16 = (f16*)alloc((size_t)H3 * H_ * 2);
    float* giA = (float*)alloc((size_t)R_ * H3 * 4);
    f16* Hhi = (f16*)alloc((size_t)R_ * H_ * 2);
    f16* Hlo = (f16*)alloc((size_t)R_ * H_ * 2);
    f16* emb16 = (f16*)alloc((size_t)V_ * H_ * 2);
    f16* ehi = (f16*)alloc((size_t)B_ * S_ * H_ * 2);
    f16* elo = (f16*)alloc((size_t)B_ * S_ * H_ * 2);
    f16* encT = (f16*)alloc((size_t)B_ * H_ * S_ * 2);
    float* lgH = (float*)alloc((size_t)R_ * S_ * 4);
    f16* ah = (f16*)alloc((size_t)R_ * S_ * 2);
    float* ctx = (float*)alloc((size_t)R_ * H_ * 4);
    float* psum = (float*)alloc((size_t)VNT * R_ * 4);

    k_init_h<<<24, 256, 0, stream>>>(hid, hbuf);
    k_prep<<<R_ + CASTB, 256, 0, stream>>>(emb, dec, tea, Wall, wih, wih16);

    // gi = W_all @ w_ih^T + b_ih
    {
        dim3 g(H3 / 128, (R_ + 127) / 128, 1);
        k_gemm<1><<<g, 256, 0, stream>>>(Wall, wih16, giA, bih, R_, H3, H_, 0, 0, 0);
    }
    // recurrence (blocks 0-191) + hidden preps on idle CUs (blocks 192-255)
    k_gru<<<256, 256, 0, stream>>>(giA, whh, bhh, hbuf, Hhi, Hlo,
                                   emb, emb16, enc, ehi, elo, encT);

    // attention logits (merged hi/lo): Hhi*Ehi + Hhi*Elo + Hlo*Ehi
    {
        dim3 g(S_ / 128, 3, 8);
        k_attn3<<<g, 256, 0, stream>>>(Hhi, Hlo, ehi, elo, lgH, 270, S_, H_,
                                       270L * H_, (long)S_ * H_, 270L * S_);
    }
    k_attn_softmax<<<R_, 256, 0, stream>>>(lgH, x, ah);
    {
        dim3 g(H_ / 128, 3, 8);
        k_gemm<0><<<g, 256, 0, stream>>>(ah, encT, ctx, nullptr, 270, H_, S_, 270L * S_, (long)H_ * S_, 270L * H_);
    }

    // vocab: out = exp(Hhi @ emb16^T), row partial sums -> psum (XCD-swizzled grid)
    k_vocab<<<VMT * VNT, 256, 0, stream>>>(Hhi, emb16, out, psum);
    // fused p_gen + rinv + finalize + pointer-scatter
    k_fin3<<<R_, 256, 0, stream>>>(out, psum, Wall, Hhi, Hlo, ctx, wgw, wgb, ah, x);
}